// Round 1
// baseline (4937.439 us; speedup 1.0000x reference)
//
#include <hip/hip_runtime.h>

// Workspace requirement: ~67 MB (agg 17.8 + deg 0.23 + W1T/W2T 1.5 + H2T 47.2).

namespace {

constexpr int NCONV = 9;
constexpr int WN    = 2784;     // 48*48 + 48*10
constexpr int OUTD  = 78;       // 48 + 10*3
constexpr int ETOT  = 82000;
constexpr float INV = 0.14433756729740643f;  // 1/sqrt(48)

constexpr int EC[NCONV]     = {15000,5000,8000,5000,10000,8000,8000,8000,15000};
constexpr int NBLKC[NCONV]  = {235,79,125,79,157,125,125,125,235};      // ceil(E/64)
constexpr int EOFF[NCONV]   = {0,15000,20000,28000,33000,43000,51000,59000,67000};
constexpr int AGGOFF[NCONV] = {0,156000,312000,468000,624000,780000,936000,2106000,3276000};
constexpr int DEGOFF[NCONV] = {0,2000,4000,6000,8000,10000,12000,27000,42000};
constexpr int NBLK_TOT = 1285;

struct ConvPtrs {
  const float* src_x[NCONV];
  const float* dst_x[NCONV];
  const float* attr[NCONV];
  const float* sh[NCONV];
  const int*   sidx[NCONV];
  const int*   didx[NCONV];
  const float* w1; const float* b1;
  const float* w2; const float* b2;
  const float* w3; const float* b3;
};

} // namespace

__device__ __forceinline__ int conv_decode(int bid, int& rem) {
  int c = 0; rem = bid;
  while (c < NCONV - 1 && rem >= NBLKC[c]) { rem -= NBLKC[c]; ++c; }
  return c;
}

// ---------------- kernel 0: transpose per-conv W1, W2 (144x144) ----------------
__global__ __launch_bounds__(256) void prep_transpose(
    const float* __restrict__ w1, const float* __restrict__ w2,
    float* __restrict__ w1t, float* __restrict__ w2t) {
  const int b = blockIdx.x;
  const int c = b >> 1;
  const float* src = ((b & 1) ? w2 : w1) + (size_t)c * 144 * 144;
  float*       dst = ((b & 1) ? w2t : w1t) + (size_t)c * 144 * 144;
  for (int idx = threadIdx.x; idx < 144 * 144; idx += 256) {
    const int i = idx / 144, o = idx - i * 144;
    dst[o * 144 + i] = src[idx];
  }
}

// ---------------- kernel 1: per-edge 2-layer MLP -> H2^T [144][ETOT] ----------------
// block = 64 edges x 4 waves; wave w computes output channels [w*36, w*36+36).
// Weight reads are wave-uniform (scalar-promoted); z reads come from LDS (pad 145
// -> bank stride 17, conflict-free) through 8-deep register chunks so LDS traffic
// is 1/36 of the FMA count.
__device__ __forceinline__ void layer144(
    const float (*in)[145], int lane, int wv,
    const float* __restrict__ wt, const float* __restrict__ bb, float acc[36]) {
#pragma unroll
  for (int co = 0; co < 36; ++co) acc[co] = bb[wv * 36 + co];
#pragma unroll 1
  for (int ic = 0; ic < 144; ic += 8) {
    float zr[8];
#pragma unroll
    for (int t = 0; t < 8; ++t) zr[t] = in[lane][ic + t];
#pragma unroll
    for (int co = 0; co < 36; ++co) {
      const float* wr = wt + (wv * 36 + co) * 144 + ic;
#pragma unroll
      for (int t = 0; t < 8; ++t) acc[co] = fmaf(zr[t], wr[t], acc[co]);
    }
  }
}

__global__ __launch_bounds__(256) void mlp_kernel(
    ConvPtrs P, const float* __restrict__ w1t, const float* __restrict__ w2t,
    float* __restrict__ h2t) {
  __shared__ float zb[64][145];
  int rem;
  const int c    = conv_decode(blockIdx.x, rem);
  const int E    = EC[c];
  const int e0   = rem * 64;
  const int lane = threadIdx.x & 63;
  const int wv   = threadIdx.x >> 6;

  const int* sidx = P.sidx[c];
  const int* didx = P.didx[c];
  const float* attr = P.attr[c];
  const float* sx   = P.src_x[c];
  const float* dx   = P.dst_x[c];

  // z = [attr | fs | fd], gathered cooperatively (edge-clamped for the tail block)
  for (int idx = threadIdx.x; idx < 64 * 48; idx += 256) {
    const int el = idx / 48, i = idx - el * 48;
    int e = e0 + el; if (e >= E) e = E - 1;
    zb[el][i] = attr[(size_t)e * 48 + i];
  }
  for (int idx = threadIdx.x; idx < 64 * 48; idx += 256) {
    const int el = idx / 48, i = idx - el * 48;
    int e = e0 + el; if (e >= E) e = E - 1;
    zb[el][48 + i] = sx[(size_t)sidx[e] * 48 + i];
  }
  for (int idx = threadIdx.x; idx < 64 * 48; idx += 256) {
    const int el = idx / 48, i = idx - el * 48;
    int e = e0 + el; if (e >= E) e = E - 1;
    zb[el][96 + i] = dx[(size_t)didx[e] * 48 + i];
  }
  __syncthreads();

  float acc[36];
  layer144(zb, lane, wv, w1t + (size_t)c * 144 * 144, P.b1 + c * 144, acc);
  __syncthreads();               // all reads of z done -> reuse buffer for h1
#pragma unroll
  for (int co = 0; co < 36; ++co) zb[lane][wv * 36 + co] = fmaxf(acc[co], 0.f);
  __syncthreads();
  layer144(zb, lane, wv, w2t + (size_t)c * 144 * 144, P.b2 + c * 144, acc);

  int e = e0 + lane; if (e >= E) e = E - 1;
  const int ge = EOFF[c] + e;    // clamped lanes duplicate edge E-1's value: benign
#pragma unroll
  for (int co = 0; co < 36; ++co)
    h2t[(size_t)(wv * 36 + co) * ETOT + ge] = fmaxf(acc[co], 0.f);
}

// ---------------- kernel 2: fused bilinear TP + scatter ----------------
// msg58[e,j] = sum_{k,i} h2[e,k] * fs[e,i] * w3[k, col(i,j)]  (+ b3 term)
// block = 64 edges (lane = edge) x 4 waves; wave w reduces k in [w*36, w*36+36)
// into 58 per-thread accumulators; cross-wave reduce via LDS ds_add_f32; wave 0
// applies sh/INV and atomically scatters 78 values + degree.
__global__ __launch_bounds__(256) void bilinear_kernel(
    ConvPtrs P, const float* __restrict__ h2t,
    float* __restrict__ agg, float* __restrict__ deg) {
  __shared__ float fsb[64][49];
  __shared__ float accb[64][59];
  int rem;
  const int c    = conv_decode(blockIdx.x, rem);
  const int E    = EC[c];
  const int e0   = rem * 64;
  const int lane = threadIdx.x & 63;
  const int wv   = threadIdx.x >> 6;
  const int e    = e0 + lane;
  const bool act = (e < E);
  const int ec   = act ? e : (E - 1);
  const int ge   = EOFF[c] + ec;

  {
    const int* sidx = P.sidx[c];
    const float* sx = P.src_x[c];
    for (int idx = threadIdx.x; idx < 64 * 48; idx += 256) {
      const int el = idx / 48, i = idx - el * 48;
      int ee = e0 + el; if (ee >= E) ee = E - 1;
      fsb[el][i] = sx[(size_t)sidx[ee] * 48 + i];
    }
  }
  for (int idx = threadIdx.x; idx < 64 * 59; idx += 256) (&accb[0][0])[idx] = 0.f;
  __syncthreads();

  float acc[58];
#pragma unroll
  for (int j = 0; j < 58; ++j) acc[j] = 0.f;

  const float* __restrict__ w3c = P.w3 + (size_t)c * 144 * WN;
  const int k0 = wv * 36;
  float hk = h2t[(size_t)k0 * ETOT + ge];
  for (int kk = 0; kk < 36; ++kk) {
    const float hkn = (kk < 35) ? h2t[(size_t)(k0 + kk + 1) * ETOT + ge] : 0.f;
    const float* __restrict__ wrow = w3c + (size_t)(k0 + kk) * WN;  // wave-uniform
#pragma unroll 2
    for (int i = 0; i < 48; ++i) {
      const float p = fsb[lane][i] * hk;
      const float* wr0 = wrow + i * 48;
#pragma unroll
      for (int j = 0; j < 48; ++j) acc[j] = fmaf(p, wr0[j], acc[j]);
      const float* wrv = wrow + 2304 + i * 10;
#pragma unroll
      for (int v = 0; v < 10; ++v) acc[48 + v] = fmaf(p, wrv[v], acc[48 + v]);
    }
    hk = hkn;
  }
  if (wv == 0) {  // b3 contribution (k-independent): one extra i-pass with p = fs_i
    const float* __restrict__ b3c = P.b3 + (size_t)c * WN;
#pragma unroll 2
    for (int i = 0; i < 48; ++i) {
      const float p = fsb[lane][i];
      const float* wr0 = b3c + i * 48;
#pragma unroll
      for (int j = 0; j < 48; ++j) acc[j] = fmaf(p, wr0[j], acc[j]);
      const float* wrv = b3c + 2304 + i * 10;
#pragma unroll
      for (int v = 0; v < 10; ++v) acc[48 + v] = fmaf(p, wrv[v], acc[48 + v]);
    }
  }
#pragma unroll
  for (int j = 0; j < 58; ++j) atomicAdd(&accb[lane][j], acc[j]);
  __syncthreads();

  if (wv == 0 && act) {
    const float* sh = P.sh[c] + (size_t)ec * 9;
    const float s0 = sh[0] * INV;
    const float s1 = sh[1], s2 = sh[2], s3 = sh[3];
    const int dst = P.didx[c][ec];
    float* ag = agg + AGGOFF[c] + (size_t)dst * OUTD;
#pragma unroll 1
    for (int j = 0; j < 48; ++j) atomicAdd(&ag[j], accb[lane][j] * s0);
#pragma unroll 1
    for (int v = 0; v < 10; ++v) {
      const float t = accb[lane][48 + v] * INV;
      atomicAdd(&ag[48 + v * 3 + 0], t * s1);
      atomicAdd(&ag[48 + v * 3 + 1], t * s2);
      atomicAdd(&ag[48 + v * 3 + 2], t * s3);
    }
    atomicAdd(&deg[DEGOFF[c] + dst], 1.0f);
  }
}

// ---------------- kernel 3: out = residual + sum_c agg_c / max(deg_c, 1) ----------------
__global__ __launch_bounds__(256) void finalize_kernel(
    const float* __restrict__ lig, const float* __restrict__ rec,
    const float* __restrict__ atom, const float* __restrict__ agg,
    const float* __restrict__ deg, float* __restrict__ out) {
  const int gid = blockIdx.x * 256 + threadIdx.x;
  if (gid >= 19000 * OUTD) return;
  const int row = gid / OUTD;
  const int j   = gid - row * OUTD;
  int node, cb; const float* x;
  if (row < 2000)      { node = row;        cb = 0; x = lig; }
  else if (row < 4000) { node = row - 2000; cb = 3; x = rec; }
  else                 { node = row - 4000; cb = 6; x = atom; }
  float r = (j < 48) ? x[(size_t)node * 48 + j] : 0.f;
#pragma unroll
  for (int t = 0; t < 3; ++t) {
    const int c = cb + t;
    const float d = deg[DEGOFF[c] + node];
    r += agg[AGGOFF[c] + (size_t)node * OUTD + j] * (1.f / fmaxf(d, 1.f));
  }
  out[gid] = r;
}

extern "C" void kernel_launch(void* const* d_in, const int* in_sizes, int n_in,
                              void* d_out, int out_size, void* d_ws, size_t ws_size,
                              hipStream_t stream) {
  (void)in_sizes; (void)n_in; (void)out_size; (void)ws_size;
  const float* lig_x  = (const float*)d_in[0];
  const float* rec_x  = (const float*)d_in[1];
  const float* atom_x = (const float*)d_in[2];
  const float* attr_ll = (const float*)d_in[3];
  const float* attr_rr = (const float*)d_in[4];
  const float* attr_aa = (const float*)d_in[5];
  const float* attr_lr = (const float*)d_in[6];
  const float* attr_la = (const float*)d_in[7];
  const float* attr_ar = (const float*)d_in[8];
  const float* sh_ll = (const float*)d_in[9];
  const float* sh_rr = (const float*)d_in[10];
  const float* sh_aa = (const float*)d_in[11];
  const float* sh_lr = (const float*)d_in[12];
  const float* sh_la = (const float*)d_in[13];
  const float* sh_ar = (const float*)d_in[14];
  const float* w1 = (const float*)d_in[15];
  const float* b1 = (const float*)d_in[16];
  const float* w2 = (const float*)d_in[17];
  const float* b2 = (const float*)d_in[18];
  const float* w3 = (const float*)d_in[19];
  const float* b3 = (const float*)d_in[20];
  const int* ll_src = (const int*)d_in[21];
  const int* ll_dst = (const int*)d_in[22];
  const int* rr_src = (const int*)d_in[23];
  const int* rr_dst = (const int*)d_in[24];
  const int* aa_src = (const int*)d_in[25];
  const int* aa_dst = (const int*)d_in[26];
  const int* lr_lig = (const int*)d_in[27];
  const int* lr_rec = (const int*)d_in[28];
  const int* la_lig = (const int*)d_in[29];
  const int* la_atom = (const int*)d_in[30];
  const int* ar_atom = (const int*)d_in[31];
  const int* ar_rec  = (const int*)d_in[32];

  float* ws  = (float*)d_ws;
  float* agg = ws;                        // 4,446,000 floats
  float* deg = agg + 4446000;             //    57,000
  float* w1t = deg + 57000;               //   186,624
  float* w2t = w1t + 186624;              //   186,624
  float* h2t = w2t + 186624;              // 11,808,000  (H2^T [144][82000])

  hipMemsetAsync(agg, 0, (size_t)(4446000 + 57000) * sizeof(float), stream);

  ConvPtrs P;
  const float* SX[NCONV] = {lig_x, rec_x, atom_x, lig_x, rec_x, atom_x, lig_x, rec_x, atom_x};
  const float* DX[NCONV] = {lig_x, lig_x, lig_x, rec_x, rec_x, rec_x, atom_x, atom_x, atom_x};
  const float* AT[NCONV] = {attr_ll, attr_lr, attr_la, attr_lr, attr_rr, attr_ar, attr_la, attr_ar, attr_aa};
  const float* SH[NCONV] = {sh_ll, sh_lr, sh_la, sh_lr, sh_rr, sh_ar, sh_la, sh_ar, sh_aa};
  const int*   SI[NCONV] = {ll_src, lr_rec, la_atom, lr_lig, rr_src, ar_atom, la_lig, ar_rec, aa_src};
  const int*   DI[NCONV] = {ll_dst, lr_lig, la_lig, lr_rec, rr_dst, ar_rec, la_atom, ar_atom, aa_dst};
  for (int c = 0; c < NCONV; ++c) {
    P.src_x[c] = SX[c]; P.dst_x[c] = DX[c]; P.attr[c] = AT[c];
    P.sh[c] = SH[c]; P.sidx[c] = SI[c]; P.didx[c] = DI[c];
  }
  P.w1 = w1; P.b1 = b1; P.w2 = w2; P.b2 = b2; P.w3 = w3; P.b3 = b3;

  prep_transpose<<<18, 256, 0, stream>>>(w1, w2, w1t, w2t);
  mlp_kernel<<<NBLK_TOT, 256, 0, stream>>>(P, w1t, w2t, h2t);
  bilinear_kernel<<<NBLK_TOT, 256, 0, stream>>>(P, h2t, agg, deg);
  finalize_kernel<<<(19000 * OUTD + 255) / 256, 256, 0, stream>>>(
      lig_x, rec_x, atom_x, agg, deg, (float*)d_out);
}

// Round 2
// 212.209 us; speedup vs baseline: 23.2669x; 23.2669x over previous
//
#include <hip/hip_runtime.h>

// Fully-fused e3nn TP-conv: per-edge MLP (fp16 MFMA) + bilinear TP (fp16 MFMA)
// + scaled atomic scatter. Workspace: ~9.9 MB (frag weights + deg).

namespace {

constexpr int NCONV = 9;
constexpr int ETOT  = 82000;
constexpr float INV = 0.14433756729740643f;  // 1/sqrt(48)

constexpr int EC[NCONV]     = {15000,5000,8000,5000,10000,8000,8000,8000,15000};
constexpr int NBLKC[NCONV]  = {118,40,63,40,79,63,63,63,118};   // ceil(E/128)
constexpr int EOFF[NCONV]   = {0,15000,20000,28000,33000,43000,51000,59000,67000};
constexpr int DEGOFF[NCONV] = {0,2000,4000,6000,8000,10000,12000,27000,42000};
constexpr int NBLK_TOT = 647;

typedef _Float16 f16;
typedef __attribute__((ext_vector_type(8))) _Float16 f16x8;
typedef __attribute__((ext_vector_type(4))) float f32x4;

#define MFMA(a, b, c) __builtin_amdgcn_mfma_f32_16x16x32_f16((a), (b), (c), 0, 0, 0)

struct ConvPtrs {
  const float* src_x[NCONV];
  const float* dst_x[NCONV];
  const float* attr[NCONV];
  const float* sh[NCONV];
  const int*   sidx[NCONV];
  const int*   didx[NCONV];
};

} // namespace

__device__ __forceinline__ int conv_decode(int bid, int& rem) {
  int c = 0; rem = bid;
  while (c < NCONV - 1 && rem >= NBLKC[c]) { rem -= NBLKC[c]; ++c; }
  return c;
}

// ---- prep: W1/W2 (144x144 +bias row) -> fragment-layout fp16 ----
// frag(c,cb,s): 512 f16; element l*8+j = B[k=s*32+(l>>4)*8+j][n=cb*16+(l&15)]
__global__ __launch_bounds__(64) void prep_w12(
    const float* __restrict__ w1, const float* __restrict__ b1,
    const float* __restrict__ w2, const float* __restrict__ b2,
    f16* __restrict__ w1f, f16* __restrict__ w2f) {
  const int b = blockIdx.x;                 // 810 = 2*9*9*5
  const int sel = b >= 405, bb = sel ? b - 405 : b;
  const int c = bb / 45, r2 = bb % 45, cb = r2 / 5, s = r2 % 5;
  const float* w  = sel ? w2 : w1;
  const float* bi = sel ? b2 : b1;
  f16* dst = (sel ? w2f : w1f) + ((size_t)(c * 9 + cb) * 5 + s) * 512;
  const int l = threadIdx.x;
  const int n = cb * 16 + (l & 15);
  f16x8 pack;
#pragma unroll
  for (int j = 0; j < 8; ++j) {
    const int k = s * 32 + ((l >> 4) << 3) + j;
    float v = 0.f;
    if (k < 144)       v = w[((size_t)c * 144 + k) * 144 + n];
    else if (k == 144) v = bi[c * 144 + n];
    pack[j] = (f16)v;
  }
  ((f16x8*)dst)[l] = pack;
}

// ---- prep: W3/b3 -> frag layout. frag(c,i,s,cb): col<48 -> w3[k][i*48+col],
// col in 48..57 -> w3[k][2304+i*10+(col-48)], col>=58 -> 0; k==144 row = b3 ----
__global__ __launch_bounds__(256) void prep_w3k(
    const float* __restrict__ w3, const float* __restrict__ b3,
    f16* __restrict__ w3f) {
  const int b = blockIdx.x;                 // 432 = 9*48
  const int c = b / 48, i = b % 48;
  const float* wc = w3 + (size_t)c * 144 * 2784;
  const float* bc = b3 + (size_t)c * 2784;
  f16* dst = w3f + (size_t)(c * 48 + i) * 20 * 512;
#pragma unroll 1
  for (int it = 0; it < 40; ++it) {
    const int f = it * 256 + threadIdx.x;   // 0..10239
    const int s = f >> 11, g2 = f & 2047, cb = g2 >> 9, l = (g2 >> 3) & 63, j = f & 7;
    const int k = s * 32 + ((l >> 4) << 3) + j;
    const int col = cb * 16 + (l & 15);
    float v = 0.f;
    if (k <= 144) {
      const float* src = (k == 144) ? bc : (wc + (size_t)k * 2784);
      if (col < 48)      v = src[i * 48 + col];
      else if (col < 58) v = src[2304 + i * 10 + (col - 48)];
    }
    dst[f] = (f16)v;
  }
}

// ---- deg: per-conv in-degree ----
__global__ __launch_bounds__(256) void deg_kernel(ConvPtrs P, float* __restrict__ deg) {
  const int gid = blockIdx.x * 256 + threadIdx.x;
  if (gid >= ETOT) return;
  int c = 0;
  while (c < NCONV - 1 && gid >= EOFF[c + 1]) ++c;
  const int e = gid - EOFF[c];
  atomicAdd(&deg[DEGOFF[c] + P.didx[c][e]], 1.0f);
}

// ---- residual init of out ----
__global__ __launch_bounds__(256) void resid_kernel(
    const float* __restrict__ lig, const float* __restrict__ rec,
    const float* __restrict__ atom, float* __restrict__ out) {
  const int gid = blockIdx.x * 256 + threadIdx.x;
  if (gid >= 19000 * 78) return;
  const int row = gid / 78, j = gid - row * 78;
  const float* x; int node;
  if (row < 2000)      { x = lig;  node = row; }
  else if (row < 4000) { x = rec;  node = row - 2000; }
  else                 { x = atom; node = row - 4000; }
  out[gid] = (j < 48) ? x[(size_t)node * 48 + j] : 0.f;
}

// ---- MLP layer: acc[rb][cb] = A(128x160, LDS frags) @ Wfrag (this wave's cbs) ----
template<int NCB, int CB0>
__device__ __forceinline__ void layer_mm(
    const f16x8* __restrict__ Av, const f16x8* __restrict__ wv,
    int c, int lane, int wr, f32x4 acc[4][5]) {
  f16x8 B[NCB][5];
#pragma unroll
  for (int cb = 0; cb < NCB; ++cb)
#pragma unroll
    for (int s = 0; s < 5; ++s)
      B[cb][s] = wv[((size_t)(c * 9 + CB0 + cb) * 5 + s) * 64 + lane];
#pragma unroll
  for (int rb = 0; rb < 4; ++rb)
#pragma unroll
    for (int cb = 0; cb < NCB; ++cb) acc[rb][cb] = (f32x4)0.0f;
#pragma unroll
  for (int s = 0; s < 5; ++s) {
    f16x8 A[4];
#pragma unroll
    for (int rb = 0; rb < 4; ++rb) A[rb] = Av[((wr * 4 + rb) * 5 + s) * 64 + lane];
#pragma unroll
    for (int rb = 0; rb < 4; ++rb)
#pragma unroll
      for (int cb = 0; cb < NCB; ++cb)
        acc[rb][cb] = MFMA(A[rb], B[cb][s], acc[rb][cb]);
  }
}

// relu + f16 + write back into A-tile (k < 144 only; pad rows persist)
template<int NCB, int CB0>
__device__ __forceinline__ void layer_wb(const f32x4 acc[4][5], f16* __restrict__ At,
                                         int lane, int wr) {
#pragma unroll
  for (int cb = 0; cb < NCB; ++cb) {
    const int k = (CB0 + cb) * 16 + (lane & 15);
    const int s = k >> 5, g = (k >> 3) & 3, j = k & 7;
#pragma unroll
    for (int rb = 0; rb < 4; ++rb)
#pragma unroll
      for (int r = 0; r < 4; ++r) {
        const int row = ((lane >> 4) << 2) + r;
        At[((((wr * 4 + rb) * 5 + s) * 4 + g) * 16 + row) * 8 + j] =
            (f16)fmaxf(acc[rb][cb][r], 0.f);
      }
  }
}

#define BILIN_STEP(i, CUR, NXT)                                                   \
  {                                                                               \
    if ((i) + 1 < 48) {                                                           \
      const size_t fb = (size_t)(c * 48 + (i) + 1) * 20;                          \
      _Pragma("unroll") for (int s = 0; s < 5; ++s)                               \
        _Pragma("unroll") for (int cb = 0; cb < 2; ++cb)                          \
          Bb##NXT[cb][s] = w3v[(fb + s * 4 + (wc * 2 + cb)) * 64 + lane];         \
    }                                                                             \
    f32x4 T[4][2];                                                                \
    _Pragma("unroll") for (int rb = 0; rb < 4; ++rb)                              \
      _Pragma("unroll") for (int cb = 0; cb < 2; ++cb) T[rb][cb] = (f32x4)0.0f;   \
    _Pragma("unroll") for (int s = 0; s < 5; ++s)                                 \
      _Pragma("unroll") for (int rb = 0; rb < 4; ++rb)                            \
        _Pragma("unroll") for (int cb = 0; cb < 2; ++cb)                          \
          T[rb][cb] = MFMA(Af[rb][s], Bb##CUR[cb][s], T[rb][cb]);                 \
    _Pragma("unroll") for (int rb = 0; rb < 4; ++rb) {                            \
      const f32x4 fs4 =                                                           \
          *(const f32x4*)&fst[i][wr * 64 + rb * 16 + ((lane >> 4) << 2)];         \
      _Pragma("unroll") for (int cb = 0; cb < 2; ++cb)                            \
        msg[rb][cb] += fs4 * T[rb][cb];                                           \
    }                                                                             \
  }

// ---- the fused conv kernel: 128 edges/block, 256 threads (2x2 wave grid) ----
__global__ __launch_bounds__(256, 2) void fused_conv(
    ConvPtrs P, const f16* __restrict__ w1f, const f16* __restrict__ w2f,
    const f16* __restrict__ w3f, const float* __restrict__ deg,
    float* __restrict__ out) {
  __shared__ f16   Atile[20480];        // [rb8][s5][g4][row16][j8] fp16 A-frags
  __shared__ float fst[48][128];        // fs transposed (fp32)
  __shared__ float shb[128][4];
  __shared__ int   sidb[128], dstb[128];
  __shared__ float invdegb[128];

  int rem; const int c = conv_decode(blockIdx.x, rem);
  const int E = EC[c], e0 = rem * 128;
  const int tid = threadIdx.x, lane = tid & 63, w = tid >> 6;
  const int wr = w >> 1, wc = w & 1;

  // stage idx / sh / 1/deg
  if (tid < 128) {
    int ec = e0 + tid; if (ec >= E) ec = E - 1;
    sidb[tid] = P.sidx[c][ec];
    const int d = P.didx[c][ec]; dstb[tid] = d;
    const float* shp = P.sh[c] + (size_t)ec * 9;
    shb[tid][0] = shp[0]; shb[tid][1] = shp[1];
    shb[tid][2] = shp[2]; shb[tid][3] = shp[3];
    invdegb[tid] = 1.f / fmaxf(deg[DEGOFF[c] + d], 1.f);
  }
  __syncthreads();

  // stage Z tile as A-frags (+ fst). z = [attr | fs | fd], k=144 -> 1 (bias), rest 0
  {
    const float* attr = P.attr[c];
    const float* sx = P.src_x[c];
    const float* dx = P.dst_x[c];
#pragma unroll 1
    for (int it = 0; it < 10; ++it) {
      const int u = it * 256 + tid, j8 = u >> 7, e = u & 127;
      int ec = e0 + e; if (ec >= E) ec = E - 1;
      float v[8];
      if (j8 < 6) {
        const float* p = attr + (size_t)ec * 48 + j8 * 8;
#pragma unroll
        for (int t = 0; t < 8; ++t) v[t] = p[t];
      } else if (j8 < 12) {
        const float* p = sx + (size_t)sidb[e] * 48 + (j8 - 6) * 8;
#pragma unroll
        for (int t = 0; t < 8; ++t) v[t] = p[t];
#pragma unroll
        for (int t = 0; t < 8; ++t) fst[(j8 - 6) * 8 + t][e] = v[t];
      } else if (j8 < 18) {
        const float* p = dx + (size_t)dstb[e] * 48 + (j8 - 12) * 8;
#pragma unroll
        for (int t = 0; t < 8; ++t) v[t] = p[t];
      } else if (j8 == 18) {
        v[0] = 1.f;
#pragma unroll
        for (int t = 1; t < 8; ++t) v[t] = 0.f;
      } else {
#pragma unroll
        for (int t = 0; t < 8; ++t) v[t] = 0.f;
      }
      f16x8 h;
#pragma unroll
      for (int t = 0; t < 8; ++t) h[t] = (f16)v[t];
      const int s = j8 >> 2, g = j8 & 3, rbg = e >> 4, row = e & 15;
      ((f16x8*)Atile)[((rbg * 5 + s) * 4 + g) * 16 + row] = h;
    }
  }
  __syncthreads();

  const f16x8* Av  = (const f16x8*)Atile;
  const f16x8* w1v = (const f16x8*)w1f;
  const f16x8* w2v = (const f16x8*)w2f;
  const f16x8* w3v = (const f16x8*)w3f;

  // MLP layer 1 (cb split 0..4 / 5..8 across wc)
  f32x4 acc[4][5];
  if (wc == 0) layer_mm<5, 0>(Av, w1v, c, lane, wr, acc);
  else         layer_mm<4, 5>(Av, w1v, c, lane, wr, acc);
  __syncthreads();
  if (wc == 0) layer_wb<5, 0>(acc, Atile, lane, wr);
  else         layer_wb<4, 5>(acc, Atile, lane, wr);
  __syncthreads();
  // MLP layer 2
  if (wc == 0) layer_mm<5, 0>(Av, w2v, c, lane, wr, acc);
  else         layer_mm<4, 5>(Av, w2v, c, lane, wr, acc);
  __syncthreads();
  if (wc == 0) layer_wb<5, 0>(acc, Atile, lane, wr);
  else         layer_wb<4, 5>(acc, Atile, lane, wr);
  __syncthreads();

  // bilinear: hoist H2 A-frags, loop 48 i-chunks with double-buffered B
  f16x8 Af[4][5];
#pragma unroll
  for (int rb = 0; rb < 4; ++rb)
#pragma unroll
    for (int s = 0; s < 5; ++s)
      Af[rb][s] = Av[((wr * 4 + rb) * 5 + s) * 64 + lane];

  f32x4 msg[4][2];
#pragma unroll
  for (int rb = 0; rb < 4; ++rb)
#pragma unroll
    for (int cb = 0; cb < 2; ++cb) msg[rb][cb] = (f32x4)0.0f;

  f16x8 Bb0[2][5], Bb1[2][5];
  {
    const size_t fb = (size_t)(c * 48) * 20;
#pragma unroll
    for (int s = 0; s < 5; ++s)
#pragma unroll
      for (int cb = 0; cb < 2; ++cb)
        Bb0[cb][s] = w3v[(fb + s * 4 + (wc * 2 + cb)) * 64 + lane];
  }
#pragma unroll 1
  for (int ii = 0; ii < 48; ii += 2) {
    BILIN_STEP(ii, 0, 1);
    BILIN_STEP(ii + 1, 1, 0);
  }

  // epilogue: scatter msg * sh * INV / deg into out
  const int outbase = (c < 3) ? 0 : (c < 6 ? 2000 : 4000);
#pragma unroll
  for (int rb = 0; rb < 4; ++rb)
#pragma unroll
    for (int r = 0; r < 4; ++r) {
      const int el = wr * 64 + rb * 16 + ((lane >> 4) << 2) + r;
      if (e0 + el >= E) continue;
      const float sc = invdegb[el] * INV;
      float* op = out + ((size_t)outbase + dstb[el]) * 78;
      const float s0 = shb[el][0], s1 = shb[el][1], s2 = shb[el][2], s3 = shb[el][3];
#pragma unroll
      for (int cb = 0; cb < 2; ++cb) {
        const int col = (wc * 2 + cb) * 16 + (lane & 15);
        const float v = msg[rb][cb][r] * sc;
        if (col < 48) {
          atomicAdd(op + col, v * s0);
        } else if (col < 58) {
          const int vv = col - 48;
          atomicAdd(op + 48 + vv * 3 + 0, v * s1);
          atomicAdd(op + 48 + vv * 3 + 1, v * s2);
          atomicAdd(op + 48 + vv * 3 + 2, v * s3);
        }
      }
    }
}

extern "C" void kernel_launch(void* const* d_in, const int* in_sizes, int n_in,
                              void* d_out, int out_size, void* d_ws, size_t ws_size,
                              hipStream_t stream) {
  (void)in_sizes; (void)n_in; (void)out_size; (void)ws_size;
  const float* lig_x  = (const float*)d_in[0];
  const float* rec_x  = (const float*)d_in[1];
  const float* atom_x = (const float*)d_in[2];
  const float* attr_ll = (const float*)d_in[3];
  const float* attr_rr = (const float*)d_in[4];
  const float* attr_aa = (const float*)d_in[5];
  const float* attr_lr = (const float*)d_in[6];
  const float* attr_la = (const float*)d_in[7];
  const float* attr_ar = (const float*)d_in[8];
  const float* sh_ll = (const float*)d_in[9];
  const float* sh_rr = (const float*)d_in[10];
  const float* sh_aa = (const float*)d_in[11];
  const float* sh_lr = (const float*)d_in[12];
  const float* sh_la = (const float*)d_in[13];
  const float* sh_ar = (const float*)d_in[14];
  const float* w1 = (const float*)d_in[15];
  const float* b1 = (const float*)d_in[16];
  const float* w2 = (const float*)d_in[17];
  const float* b2 = (const float*)d_in[18];
  const float* w3 = (const float*)d_in[19];
  const float* b3 = (const float*)d_in[20];
  const int* ll_src = (const int*)d_in[21];
  const int* ll_dst = (const int*)d_in[22];
  const int* rr_src = (const int*)d_in[23];
  const int* rr_dst = (const int*)d_in[24];
  const int* aa_src = (const int*)d_in[25];
  const int* aa_dst = (const int*)d_in[26];
  const int* lr_lig = (const int*)d_in[27];
  const int* lr_rec = (const int*)d_in[28];
  const int* la_lig = (const int*)d_in[29];
  const int* la_atom = (const int*)d_in[30];
  const int* ar_atom = (const int*)d_in[31];
  const int* ar_rec  = (const int*)d_in[32];

  f16* w1f = (f16*)d_ws;                    //   207,360 f16
  f16* w2f = w1f + 207360;                  //   207,360 f16
  f16* w3f = w2f + 207360;                  // 4,423,680 f16
  float* deg = (float*)(w3f + 4423680);     //    57,000 f32

  ConvPtrs P;
  const float* SX[NCONV] = {lig_x, rec_x, atom_x, lig_x, rec_x, atom_x, lig_x, rec_x, atom_x};
  const float* DX[NCONV] = {lig_x, lig_x, lig_x, rec_x, rec_x, rec_x, atom_x, atom_x, atom_x};
  const float* AT[NCONV] = {attr_ll, attr_lr, attr_la, attr_lr, attr_rr, attr_ar, attr_la, attr_ar, attr_aa};
  const float* SH[NCONV] = {sh_ll, sh_lr, sh_la, sh_lr, sh_rr, sh_ar, sh_la, sh_ar, sh_aa};
  const int*   SI[NCONV] = {ll_src, lr_rec, la_atom, lr_lig, rr_src, ar_atom, la_lig, ar_rec, aa_src};
  const int*   DI[NCONV] = {ll_dst, lr_lig, la_lig, lr_rec, rr_dst, ar_rec, la_atom, ar_atom, aa_dst};
  for (int cc = 0; cc < NCONV; ++cc) {
    P.src_x[cc] = SX[cc]; P.dst_x[cc] = DX[cc]; P.attr[cc] = AT[cc];
    P.sh[cc] = SH[cc]; P.sidx[cc] = SI[cc]; P.didx[cc] = DI[cc];
  }

  prep_w12<<<810, 64, 0, stream>>>(w1, b1, w2, b2, w1f, w2f);
  prep_w3k<<<432, 256, 0, stream>>>(w3, b3, w3f);
  hipMemsetAsync(deg, 0, 57000 * sizeof(float), stream);
  deg_kernel<<<(ETOT + 255) / 256, 256, 0, stream>>>(P, deg);
  resid_kernel<<<(19000 * 78 + 255) / 256, 256, 0, stream>>>(lig_x, rec_x, atom_x, (float*)d_out);
  fused_conv<<<NBLK_TOT, 256, 0, stream>>>(P, w1f, w2f, w3f, deg, (float*)d_out);
}

// Round 3
// 202.903 us; speedup vs baseline: 24.3340x; 1.0459x over previous
//
#include <hip/hip_runtime.h>

// Fully-fused e3nn TP-conv: per-edge MLP (fp16 MFMA) + bilinear TP (fp16 MFMA)
// + scaled atomic scatter. R3: 3 blocks/CU (LDS 54272 B, all 647 blocks
// co-resident), Atile LDS reused as double-buffered w3 B-stage via
// global_load_lds, Af forced register-resident. Workspace ~9.9 MB.

namespace {

constexpr int NCONV = 9;
constexpr int ETOT  = 82000;
constexpr float INV = 0.14433756729740643f;  // 1/sqrt(48)

constexpr int EC[NCONV]     = {15000,5000,8000,5000,10000,8000,8000,8000,15000};
constexpr int NBLKC[NCONV]  = {118,40,63,40,79,63,63,63,118};   // ceil(E/128)
constexpr int EOFF[NCONV]   = {0,15000,20000,28000,33000,43000,51000,59000,67000};
constexpr int DEGOFF[NCONV] = {0,2000,4000,6000,8000,10000,12000,27000,42000};
constexpr int NBLK_TOT = 647;

typedef _Float16 f16;
typedef __attribute__((ext_vector_type(8))) _Float16 f16x8;
typedef __attribute__((ext_vector_type(4))) _Float16 f16x4;
typedef __attribute__((ext_vector_type(4))) float f32x4;

#define MFMA(a, b, c) __builtin_amdgcn_mfma_f32_16x16x32_f16((a), (b), (c), 0, 0, 0)

struct ConvPtrs {
  const float* src_x[NCONV];
  const float* dst_x[NCONV];
  const float* attr[NCONV];
  const float* sh[NCONV];
  const int*   sidx[NCONV];
  const int*   didx[NCONV];
};

} // namespace

__device__ __forceinline__ int conv_decode(int bid, int& rem) {
  int c = 0; rem = bid;
  while (c < NCONV - 1 && rem >= NBLKC[c]) { rem -= NBLKC[c]; ++c; }
  return c;
}

__device__ __forceinline__ void gld_lds16(const void* g, void* l) {
  __builtin_amdgcn_global_load_lds(
      (const __attribute__((address_space(1))) void*)g,
      (__attribute__((address_space(3))) void*)l, 16, 0, 0);
}

__device__ __forceinline__ f32x4 cvt4(f16x4 h) {
  return (f32x4){(float)h[0], (float)h[1], (float)h[2], (float)h[3]};
}

// ---- prep: W1/W2 (144x144 +bias row) -> fragment-layout fp16 ----
// frag(c,cb,s): 512 f16; element l*8+j = B[k=s*32+(l>>4)*8+j][n=cb*16+(l&15)]
__global__ __launch_bounds__(64) void prep_w12(
    const float* __restrict__ w1, const float* __restrict__ b1,
    const float* __restrict__ w2, const float* __restrict__ b2,
    f16* __restrict__ w1f, f16* __restrict__ w2f) {
  const int b = blockIdx.x;                 // 810 = 2*9*9*5
  const int sel = b >= 405, bb = sel ? b - 405 : b;
  const int c = bb / 45, r2 = bb % 45, cb = r2 / 5, s = r2 % 5;
  const float* w  = sel ? w2 : w1;
  const float* bi = sel ? b2 : b1;
  f16* dst = (sel ? w2f : w1f) + ((size_t)(c * 9 + cb) * 5 + s) * 512;
  const int l = threadIdx.x;
  const int n = cb * 16 + (l & 15);
  f16x8 pack;
#pragma unroll
  for (int j = 0; j < 8; ++j) {
    const int k = s * 32 + ((l >> 4) << 3) + j;
    float v = 0.f;
    if (k < 144)       v = w[((size_t)c * 144 + k) * 144 + n];
    else if (k == 144) v = bi[c * 144 + n];
    pack[j] = (f16)v;
  }
  ((f16x8*)dst)[l] = pack;
}

// ---- prep: W3/b3 -> frag layout. frag(c,i,s,cb): col<48 -> w3[k][i*48+col],
// col in 48..57 -> w3[k][2304+i*10+(col-48)], col>=58 -> 0; k==144 row = b3 ----
__global__ __launch_bounds__(256) void prep_w3k(
    const float* __restrict__ w3, const float* __restrict__ b3,
    f16* __restrict__ w3f) {
  const int b = blockIdx.x;                 // 432 = 9*48
  const int c = b / 48, i = b % 48;
  const float* wc = w3 + (size_t)c * 144 * 2784;
  const float* bc = b3 + (size_t)c * 2784;
  f16* dst = w3f + (size_t)(c * 48 + i) * 20 * 512;
#pragma unroll 1
  for (int it = 0; it < 40; ++it) {
    const int f = it * 256 + threadIdx.x;   // 0..10239
    const int s = f >> 11, g2 = f & 2047, cb = g2 >> 9, l = (g2 >> 3) & 63, j = f & 7;
    const int k = s * 32 + ((l >> 4) << 3) + j;
    const int col = cb * 16 + (l & 15);
    float v = 0.f;
    if (k <= 144) {
      const float* src = (k == 144) ? bc : (wc + (size_t)k * 2784);
      if (col < 48)      v = src[i * 48 + col];
      else if (col < 58) v = src[2304 + i * 10 + (col - 48)];
    }
    dst[f] = (f16)v;
  }
}

// ---- deg: per-conv in-degree ----
__global__ __launch_bounds__(256) void deg_kernel(ConvPtrs P, float* __restrict__ deg) {
  const int gid = blockIdx.x * 256 + threadIdx.x;
  if (gid >= ETOT) return;
  int c = 0;
  while (c < NCONV - 1 && gid >= EOFF[c + 1]) ++c;
  const int e = gid - EOFF[c];
  atomicAdd(&deg[DEGOFF[c] + P.didx[c][e]], 1.0f);
}

// ---- residual init of out ----
__global__ __launch_bounds__(256) void resid_kernel(
    const float* __restrict__ lig, const float* __restrict__ rec,
    const float* __restrict__ atom, float* __restrict__ out) {
  const int gid = blockIdx.x * 256 + threadIdx.x;
  if (gid >= 19000 * 78) return;
  const int row = gid / 78, j = gid - row * 78;
  const float* x; int node;
  if (row < 2000)      { x = lig;  node = row; }
  else if (row < 4000) { x = rec;  node = row - 2000; }
  else                 { x = atom; node = row - 4000; }
  out[gid] = (j < 48) ? x[(size_t)node * 48 + j] : 0.f;
}

// ---- MLP layer: acc[rb][cb] = A(128x160, LDS frags) @ Wfrag (this wave's cbs).
// s-outer streaming keeps B at NCB regs/step (not NCB*5).
template<int NCB, int CB0>
__device__ __forceinline__ void layer_mm(
    const f16x8* __restrict__ Av, const f16x8* __restrict__ wv,
    int c, int lane, int wr, f32x4 acc[4][5]) {
#pragma unroll
  for (int rb = 0; rb < 4; ++rb)
#pragma unroll
    for (int cb = 0; cb < NCB; ++cb) acc[rb][cb] = (f32x4)0.0f;
#pragma unroll
  for (int s = 0; s < 5; ++s) {
    f16x8 B[NCB];
#pragma unroll
    for (int cb = 0; cb < NCB; ++cb)
      B[cb] = wv[((size_t)(c * 9 + CB0 + cb) * 5 + s) * 64 + lane];
    f16x8 A[4];
#pragma unroll
    for (int rb = 0; rb < 4; ++rb) A[rb] = Av[((wr * 4 + rb) * 5 + s) * 64 + lane];
#pragma unroll
    for (int rb = 0; rb < 4; ++rb)
#pragma unroll
      for (int cb = 0; cb < NCB; ++cb)
        acc[rb][cb] = MFMA(A[rb], B[cb], acc[rb][cb]);
  }
}

// relu + f16 + write back into A-tile (k < 144 only; pad rows persist)
template<int NCB, int CB0>
__device__ __forceinline__ void layer_wb(const f32x4 acc[4][5], f16* __restrict__ At,
                                         int lane, int wr) {
#pragma unroll
  for (int cb = 0; cb < NCB; ++cb) {
    const int k = (CB0 + cb) * 16 + (lane & 15);
    const int s = k >> 5, g = (k >> 3) & 3, j = k & 7;
#pragma unroll
    for (int rb = 0; rb < 4; ++rb)
#pragma unroll
      for (int r = 0; r < 4; ++r) {
        const int row = ((lane >> 4) << 2) + r;
        At[((((wr * 4 + rb) * 5 + s) * 4 + g) * 16 + row) * 8 + j] =
            (f16)fmaxf(acc[rb][cb][r], 0.f);
      }
  }
}

// ---- the fused conv kernel: 128 edges/block, 256 threads (2x2 wave grid) ----
__global__ __launch_bounds__(256, 3) void fused_conv(
    ConvPtrs P, const f16* __restrict__ w1f, const f16* __restrict__ w2f,
    const f16* __restrict__ w3f, const float* __restrict__ deg,
    float* __restrict__ out) {
  // 0..40960      : Atile (MLP A-frags) -> reused as 2x20480 B w3 B-stage
  // 40960..53248  : fst f16[48][128]
  // 53248..54272  : sidb[128], dstb[128]
  __shared__ __align__(16) char smem[54272];
  f16* Atile = (f16*)smem;
  f16 (*fst)[128] = (f16 (*)[128])(smem + 40960);
  int* sidb = (int*)(smem + 53248);
  int* dstb = (int*)(smem + 53760);

  int rem; const int c = conv_decode(blockIdx.x, rem);
  const int E = EC[c], e0 = rem * 128;
  const int tid = threadIdx.x, lane = tid & 63, w = tid >> 6;
  const int wr = w >> 1, wc = w & 1;

  if (tid < 128) {
    int ec = e0 + tid; if (ec >= E) ec = E - 1;
    sidb[tid] = P.sidx[c][ec];
    dstb[tid] = P.didx[c][ec];
  }
  __syncthreads();

  // stage Z tile as A-frags (+ fst f16). z = [attr|fs|fd], k=144 -> 1 (bias)
  {
    const float* attr = P.attr[c];
    const float* sx = P.src_x[c];
    const float* dx = P.dst_x[c];
#pragma unroll 1
    for (int it = 0; it < 10; ++it) {
      const int u = it * 256 + tid, j8 = u >> 7, e = u & 127;
      int ec = e0 + e; if (ec >= E) ec = E - 1;
      float v[8];
      if (j8 < 6) {
        const float* p = attr + (size_t)ec * 48 + j8 * 8;
#pragma unroll
        for (int t = 0; t < 8; ++t) v[t] = p[t];
      } else if (j8 < 12) {
        const float* p = sx + (size_t)sidb[e] * 48 + (j8 - 6) * 8;
#pragma unroll
        for (int t = 0; t < 8; ++t) v[t] = p[t];
#pragma unroll
        for (int t = 0; t < 8; ++t) fst[(j8 - 6) * 8 + t][e] = (f16)v[t];
      } else if (j8 < 18) {
        const float* p = dx + (size_t)dstb[e] * 48 + (j8 - 12) * 8;
#pragma unroll
        for (int t = 0; t < 8; ++t) v[t] = p[t];
      } else if (j8 == 18) {
        v[0] = 1.f;
#pragma unroll
        for (int t = 1; t < 8; ++t) v[t] = 0.f;
      } else {
#pragma unroll
        for (int t = 0; t < 8; ++t) v[t] = 0.f;
      }
      f16x8 h;
#pragma unroll
      for (int t = 0; t < 8; ++t) h[t] = (f16)v[t];
      const int s = j8 >> 2, g = j8 & 3, rbg = e >> 4, row = e & 15;
      ((f16x8*)Atile)[((rbg * 5 + s) * 4 + g) * 16 + row] = h;
    }
  }
  __syncthreads();

  const f16x8* Av = (const f16x8*)Atile;

  // MLP (cb split 0..4 / 5..8 across wc)
  f32x4 acc[4][5];
  if (wc == 0) layer_mm<5, 0>(Av, (const f16x8*)w1f, c, lane, wr, acc);
  else         layer_mm<4, 5>(Av, (const f16x8*)w1f, c, lane, wr, acc);
  __syncthreads();
  if (wc == 0) layer_wb<5, 0>(acc, Atile, lane, wr);
  else         layer_wb<4, 5>(acc, Atile, lane, wr);
  __syncthreads();
  if (wc == 0) layer_mm<5, 0>(Av, (const f16x8*)w2f, c, lane, wr, acc);
  else         layer_mm<4, 5>(Av, (const f16x8*)w2f, c, lane, wr, acc);
  __syncthreads();
  if (wc == 0) layer_wb<5, 0>(acc, Atile, lane, wr);
  else         layer_wb<4, 5>(acc, Atile, lane, wr);
  __syncthreads();

  // hoist H2 A-frags to registers; Atile LDS is dead afterwards
  f16x8 Af[4][5];
#pragma unroll
  for (int rb = 0; rb < 4; ++rb)
#pragma unroll
    for (int s = 0; s < 5; ++s)
      Af[rb][s] = Av[((wr * 4 + rb) * 5 + s) * 64 + lane];
  __syncthreads();   // hoist reads complete before B-stage overwrites

  // bilinear: 48 i-chunks, B double-buffered in the freed Atile LDS
  const f16* __restrict__ w3c = w3f + (size_t)(c * 48) * 10240;
  f16* buf0 = Atile;
  f16* buf1 = Atile + 10240;

  f32x4 msg[4][2];
#pragma unroll
  for (int rb = 0; rb < 4; ++rb)
#pragma unroll
    for (int cb = 0; cb < 2; ++cb) msg[rb][cb] = (f32x4)0.0f;

  // prologue: stage i=0 (each wave stages 5 of 20 1KB chunks)
#pragma unroll
  for (int q = 0; q < 5; ++q) {
    const int chunk = q * 4 + w;
    gld_lds16(w3c + chunk * 512 + lane * 8, buf0 + chunk * 512);
  }
  __syncthreads();

#pragma unroll 1
  for (int i = 0; i < 48; ++i) {
    f16* bcur = (i & 1) ? buf1 : buf0;
    f16* bnxt = (i & 1) ? buf0 : buf1;
    if (i + 1 < 48) {
      const f16* gsrc = w3c + (size_t)(i + 1) * 10240;
#pragma unroll
      for (int q = 0; q < 5; ++q) {
        const int chunk = q * 4 + w;
        gld_lds16(gsrc + chunk * 512 + lane * 8, bnxt + chunk * 512);
      }
    }
    // fs for this i (f16x4 broadcast per rb)
    f16x4 fsh[4];
#pragma unroll
    for (int rb = 0; rb < 4; ++rb)
      fsh[rb] = *(const f16x4*)&fst[i][wr * 64 + rb * 16 + ((lane >> 4) << 2)];

    const f16x8* bv = (const f16x8*)bcur;
#pragma unroll
    for (int cb = 0; cb < 2; ++cb) {
      f16x8 Bf[5];
#pragma unroll
      for (int s = 0; s < 5; ++s) Bf[s] = bv[(s * 4 + wc * 2 + cb) * 64 + lane];
      f32x4 T[4];
#pragma unroll
      for (int rb = 0; rb < 4; ++rb) T[rb] = (f32x4)0.0f;
#pragma unroll
      for (int s = 0; s < 5; ++s)
#pragma unroll
        for (int rb = 0; rb < 4; ++rb) T[rb] = MFMA(Af[rb][s], Bf[s], T[rb]);
#pragma unroll
      for (int rb = 0; rb < 4; ++rb) msg[rb][cb] += cvt4(fsh[rb]) * T[rb];
    }
    __syncthreads();   // drains vmcnt (stage i+1 landed) + lgkm; flips buffers
  }

  // epilogue: scatter msg * sh * INV / deg into out
  const int outbase = (c < 3) ? 0 : (c < 6 ? 2000 : 4000);
  const float* __restrict__ shp = P.sh[c];
  const float* __restrict__ degc = deg + DEGOFF[c];
#pragma unroll
  for (int rb = 0; rb < 4; ++rb)
#pragma unroll
    for (int r = 0; r < 4; ++r) {
      const int el = wr * 64 + rb * 16 + ((lane >> 4) << 2) + r;
      const int ec = e0 + el;
      if (ec >= E) continue;
      const int dst = dstb[el];
      const float sc = INV / fmaxf(degc[dst], 1.f);
      const float* shq = shp + (size_t)ec * 9;
      const float s0 = shq[0], s1 = shq[1], s2 = shq[2], s3 = shq[3];
      float* op = out + ((size_t)outbase + dst) * 78;
#pragma unroll
      for (int cb = 0; cb < 2; ++cb) {
        const int col = (wc * 2 + cb) * 16 + (lane & 15);
        const float v = msg[rb][cb][r] * sc;
        if (col < 48) {
          atomicAdd(op + col, v * s0);
        } else if (col < 58) {
          const int vv = col - 48;
          atomicAdd(op + 48 + vv * 3 + 0, v * s1);
          atomicAdd(op + 48 + vv * 3 + 1, v * s2);
          atomicAdd(op + 48 + vv * 3 + 2, v * s3);
        }
      }
    }
}

extern "C" void kernel_launch(void* const* d_in, const int* in_sizes, int n_in,
                              void* d_out, int out_size, void* d_ws, size_t ws_size,
                              hipStream_t stream) {
  (void)in_sizes; (void)n_in; (void)out_size; (void)ws_size;
  const float* lig_x  = (const float*)d_in[0];
  const float* rec_x  = (const float*)d_in[1];
  const float* atom_x = (const float*)d_in[2];
  const float* attr_ll = (const float*)d_in[3];
  const float* attr_rr = (const float*)d_in[4];
  const float* attr_aa = (const float*)d_in[5];
  const float* attr_lr = (const float*)d_in[6];
  const float* attr_la = (const float*)d_in[7];
  const float* attr_ar = (const float*)d_in[8];
  const float* sh_ll = (const float*)d_in[9];
  const float* sh_rr = (const float*)d_in[10];
  const float* sh_aa = (const float*)d_in[11];
  const float* sh_lr = (const float*)d_in[12];
  const float* sh_la = (const float*)d_in[13];
  const float* sh_ar = (const float*)d_in[14];
  const float* w1 = (const float*)d_in[15];
  const float* b1 = (const float*)d_in[16];
  const float* w2 = (const float*)d_in[17];
  const float* b2 = (const float*)d_in[18];
  const float* w3 = (const float*)d_in[19];
  const float* b3 = (const float*)d_in[20];
  const int* ll_src = (const int*)d_in[21];
  const int* ll_dst = (const int*)d_in[22];
  const int* rr_src = (const int*)d_in[23];
  const int* rr_dst = (const int*)d_in[24];
  const int* aa_src = (const int*)d_in[25];
  const int* aa_dst = (const int*)d_in[26];
  const int* lr_lig = (const int*)d_in[27];
  const int* lr_rec = (const int*)d_in[28];
  const int* la_lig = (const int*)d_in[29];
  const int* la_atom = (const int*)d_in[30];
  const int* ar_atom = (const int*)d_in[31];
  const int* ar_rec  = (const int*)d_in[32];

  f16* w1f = (f16*)d_ws;                    //   207,360 f16
  f16* w2f = w1f + 207360;                  //   207,360 f16
  f16* w3f = w2f + 207360;                  // 4,423,680 f16
  float* deg = (float*)(w3f + 4423680);     //    57,000 f32

  ConvPtrs P;
  const float* SX[NCONV] = {lig_x, rec_x, atom_x, lig_x, rec_x, atom_x, lig_x, rec_x, atom_x};
  const float* DX[NCONV] = {lig_x, lig_x, lig_x, rec_x, rec_x, rec_x, atom_x, atom_x, atom_x};
  const float* AT[NCONV] = {attr_ll, attr_lr, attr_la, attr_lr, attr_rr, attr_ar, attr_la, attr_ar, attr_aa};
  const float* SH[NCONV] = {sh_ll, sh_lr, sh_la, sh_lr, sh_rr, sh_ar, sh_la, sh_ar, sh_aa};
  const int*   SI[NCONV] = {ll_src, lr_rec, la_atom, lr_lig, rr_src, ar_atom, la_lig, ar_rec, aa_src};
  const int*   DI[NCONV] = {ll_dst, lr_lig, la_lig, lr_rec, rr_dst, ar_rec, la_atom, ar_atom, aa_dst};
  for (int cc = 0; cc < NCONV; ++cc) {
    P.src_x[cc] = SX[cc]; P.dst_x[cc] = DX[cc]; P.attr[cc] = AT[cc];
    P.sh[cc] = SH[cc]; P.sidx[cc] = SI[cc]; P.didx[cc] = DI[cc];
  }

  prep_w12<<<810, 64, 0, stream>>>(w1, b1, w2, b2, w1f, w2f);
  prep_w3k<<<432, 256, 0, stream>>>(w3, b3, w3f);
  hipMemsetAsync(deg, 0, 57000 * sizeof(float), stream);
  deg_kernel<<<(ETOT + 255) / 256, 256, 0, stream>>>(P, deg);
  resid_kernel<<<(19000 * 78 + 255) / 256, 256, 0, stream>>>(lig_x, rec_x, atom_x, (float*)d_out);
  fused_conv<<<NBLK_TOT, 256, 0, stream>>>(P, w1f, w2f, w3f, deg, (float*)d_out);
}